// Round 1
// baseline (995.637 us; speedup 1.0000x reference)
//
#include <hip/hip_runtime.h>

#define HID 2048
#define INTER 1408
#define NEXP 14
#define SINTER 2816
#define TTOK 2048

typedef short bf16x8 __attribute__((ext_vector_type(8)));
typedef float f32x4 __attribute__((ext_vector_type(4)));
typedef unsigned short u16x8 __attribute__((ext_vector_type(8)));

__device__ __forceinline__ unsigned short f2bf(float f) {
    __bf16 b = (__bf16)f;
    return __builtin_bit_cast(unsigned short, b);
}
// XOR swizzle for tiles with 128B row stride (64 bf16 per row)
__device__ __forceinline__ unsigned swz(unsigned b) { return b ^ (((b >> 7) & 7u) << 4); }

__global__ void k_zero(int* cnt) {
    if ((int)threadIdx.x < NEXP) cnt[threadIdx.x] = 0;
}

__global__ __launch_bounds__(256) void k_xcvt(const float* __restrict__ x,
                                              unsigned short* __restrict__ xb) {
    size_t i = ((size_t)blockIdx.x * 256 + threadIdx.x) * 8;
    float4 a = *(const float4*)(x + i);
    float4 b = *(const float4*)(x + i + 4);
    u16x8 v;
    v[0] = f2bf(a.x); v[1] = f2bf(a.y); v[2] = f2bf(a.z); v[3] = f2bf(a.w);
    v[4] = f2bf(b.x); v[5] = f2bf(b.y); v[6] = f2bf(b.z); v[7] = f2bf(b.w);
    *(u16x8*)(xb + i) = v;
}

// One wave per token. fp32 throughout (matches reference router numerics closely).
__global__ __launch_bounds__(256) void k_router(
    const float* __restrict__ x,
    const float* __restrict__ gate_w, const float* __restrict__ cls_w,
    const float* __restrict__ escale, const float* __restrict__ ebias,
    int* __restrict__ cnt, int* __restrict__ etok, float* __restrict__ ew) {
    const int lane = threadIdx.x & 63;
    const int tok = blockIdx.x * 4 + (threadIdx.x >> 6);
    const float* xr = x + (size_t)tok * HID;
    float xv[32];
#pragma unroll
    for (int i = 0; i < 32; i++) xv[i] = xr[lane + 64 * i];

    float sc[NEXP];
    float mx = 0.f;
#pragma unroll
    for (int e = 0; e < NEXP; e++) {
        const float* cw = cls_w + (size_t)e * HID;
        const float* gw = gate_w + (size_t)e * HID;
        float pc = 0.f, pg = 0.f;
#pragma unroll
        for (int i = 0; i < 32; i++) {
            float v = xv[i];
            pc = fmaf(v, cw[lane + 64 * i], pc);
            pg = fmaf(v, gw[lane + 64 * i], pg);
        }
#pragma unroll
        for (int o = 32; o >= 1; o >>= 1) {
            pc += __shfl_xor(pc, o);
            pg += __shfl_xor(pg, o);
        }
        float lg = pc * (pg / (1.f + __expf(-pg)));   // cls * silu(gate)
        sc[e] = fabsf(lg);
        mx = fmaxf(mx, sc[e]);
    }
    float s = 0.f;
#pragma unroll
    for (int e = 0; e < NEXP; e++) { sc[e] = __expf(sc[e] - mx); s += sc[e]; }
    float inv = 1.f / s;
    // top-2 on (score + bias); strict > keeps lowest index on ties (jax top_k semantics)
    int i1 = -1, i2 = -1;
    float b1 = -1e30f, b2 = -1e30f, v1 = 0.f, v2 = 0.f;
#pragma unroll
    for (int e = 0; e < NEXP; e++) {
        float sv = sc[e] * inv;
        float b = sv + ebias[e];
        if (b > b1) { b2 = b1; i2 = i1; v2 = v1; b1 = b; i1 = e; v1 = sv; }
        else if (b > b2) { b2 = b; i2 = e; v2 = sv; }
    }
    if (lane == 0) {
        float w1 = 1.f + v1 * escale[i1];
        float w2 = 1.f + v2 * escale[i2];
        int p1 = atomicAdd(&cnt[i1], 1);
        etok[i1 * TTOK + p1] = tok * 2;     ew[i1 * TTOK + p1] = w1;
        int p2 = atomicAdd(&cnt[i2], 1);
        etok[i2 * TTOK + p2] = tok * 2 + 1; ew[i2 * TTOK + p2] = w2;
    }
}

__global__ void k_offsets(const int* __restrict__ cnt, int* __restrict__ offs) {
    if (threadIdx.x == 0) {
        int a = 0;
        for (int e = 0; e < NEXP; e++) { offs[e] = a; a += cnt[e]; }
    }
}

// Fused gate+up GEMM + SwiGLU epilogue. BM=128, BN=64 (per matrix), BK=64, 256 thr.
// A (x, bf16) gathered rows; B (wg/wu, fp32 [N][K]) converted to bf16 in regs.
template <bool ROUTED>
__global__ __launch_bounds__(256) void k_glu(
    const unsigned short* __restrict__ xb,
    const float* __restrict__ Wgb, const float* __restrict__ Wub,
    unsigned short* __restrict__ hout,
    const int* __restrict__ cnt, const int* __restrict__ offs,
    const int* __restrict__ etok) {
    constexpr int Kd = HID;
    constexpr int KT = Kd / 64;
    constexpr int Ntot = ROUTED ? INTER : SINTER;
    const int e = ROUTED ? blockIdx.z : 0;
    const int n0 = blockIdx.x * 64;
    const int m0 = blockIdx.y * 128;
    int M, obase;
    if (ROUTED) {
        M = cnt[e];
        if (m0 >= M) return;
        obase = offs[e];
    } else { M = TTOK; obase = 0; }

    const float* wg = Wgb + (size_t)e * INTER * HID + (size_t)n0 * Kd;
    const float* wu = Wub + (size_t)e * INTER * HID + (size_t)n0 * Kd;

    __shared__ alignas(16) unsigned short sA[128 * 64];
    __shared__ alignas(16) unsigned short sBg[64 * 64];
    __shared__ alignas(16) unsigned short sBu[64 * 64];

    const int t = threadIdx.x;

    const unsigned short* srcA[4];
    unsigned wAo[4];
#pragma unroll
    for (int p = 0; p < 4; p++) {
        int r = p * 32 + (t >> 3);
        int row = m0 + r;
        int tokr;
        if (ROUTED) tokr = (row < M) ? (etok[e * TTOK + row] >> 1) : (etok[e * TTOK] >> 1);
        else        tokr = row;
        srcA[p] = xb + (size_t)tokr * HID + (t & 7) * 8;
        wAo[p] = swz((unsigned)(r * 128 + (t & 7) * 16));
    }
    const float* srcG[4];
    const float* srcU[4];
    unsigned wBo[4];
#pragma unroll
    for (int p = 0; p < 4; p++) {
        int r = p * 16 + (t >> 4);
        srcG[p] = wg + (size_t)r * Kd + (t & 15) * 4;
        srcU[p] = wu + (size_t)r * Kd + (t & 15) * 4;
        wBo[p] = swz((unsigned)(r * 128 + (t & 15) * 8));
    }

    uint4 ra[4]; float4 rg[4]; float4 ru[4];
    auto load = [&](int k0) {
#pragma unroll
        for (int p = 0; p < 4; p++) ra[p] = *(const uint4*)(srcA[p] + k0);
#pragma unroll
        for (int p = 0; p < 4; p++) rg[p] = *(const float4*)(srcG[p] + k0);
#pragma unroll
        for (int p = 0; p < 4; p++) ru[p] = *(const float4*)(srcU[p] + k0);
    };
    auto store = [&]() {
#pragma unroll
        for (int p = 0; p < 4; p++) *(uint4*)((char*)sA + wAo[p]) = ra[p];
#pragma unroll
        for (int p = 0; p < 4; p++) {
            ushort4 v;
            v.x = f2bf(rg[p].x); v.y = f2bf(rg[p].y); v.z = f2bf(rg[p].z); v.w = f2bf(rg[p].w);
            *(ushort4*)((char*)sBg + wBo[p]) = v;
        }
#pragma unroll
        for (int p = 0; p < 4; p++) {
            ushort4 v;
            v.x = f2bf(ru[p].x); v.y = f2bf(ru[p].y); v.z = f2bf(ru[p].z); v.w = f2bf(ru[p].w);
            *(ushort4*)((char*)sBu + wBo[p]) = v;
        }
    };

    const int lane = t & 63;
    const int wid = t >> 6;
    const int wm = wid >> 1, wn = wid & 1;
    const int fr = lane & 15, fo = lane >> 4;

    unsigned aoff[4][2], boff[2][2];
#pragma unroll
    for (int mi = 0; mi < 4; mi++)
#pragma unroll
        for (int ks = 0; ks < 2; ks++)
            aoff[mi][ks] = swz((unsigned)((wm * 64 + mi * 16 + fr) * 128 + ks * 64 + fo * 16));
#pragma unroll
    for (int nj = 0; nj < 2; nj++)
#pragma unroll
        for (int ks = 0; ks < 2; ks++)
            boff[nj][ks] = swz((unsigned)((wn * 32 + nj * 16 + fr) * 128 + ks * 64 + fo * 16));

    f32x4 ag[4][2], au[4][2];
#pragma unroll
    for (int mi = 0; mi < 4; mi++)
#pragma unroll
        for (int nj = 0; nj < 2; nj++) {
            ag[mi][nj] = {0.f, 0.f, 0.f, 0.f};
            au[mi][nj] = {0.f, 0.f, 0.f, 0.f};
        }

    load(0);
    store();
    __syncthreads();
    for (int kk = 0; kk < KT; ++kk) {
        if (kk + 1 < KT) load((kk + 1) * 64);
#pragma unroll
        for (int ks = 0; ks < 2; ++ks) {
            bf16x8 af[4], gf[2], uf[2];
#pragma unroll
            for (int mi = 0; mi < 4; mi++)
                af[mi] = *(const bf16x8*)((const char*)sA + aoff[mi][ks]);
#pragma unroll
            for (int nj = 0; nj < 2; nj++) {
                gf[nj] = *(const bf16x8*)((const char*)sBg + boff[nj][ks]);
                uf[nj] = *(const bf16x8*)((const char*)sBu + boff[nj][ks]);
            }
#pragma unroll
            for (int mi = 0; mi < 4; mi++)
#pragma unroll
                for (int nj = 0; nj < 2; nj++) {
                    ag[mi][nj] = __builtin_amdgcn_mfma_f32_16x16x32_bf16(af[mi], gf[nj], ag[mi][nj], 0, 0, 0);
                    au[mi][nj] = __builtin_amdgcn_mfma_f32_16x16x32_bf16(af[mi], uf[nj], au[mi][nj], 0, 0, 0);
                }
        }
        __syncthreads();
        if (kk + 1 < KT) store();
        __syncthreads();
    }

    // epilogue: h = silu(g) * u, store bf16
#pragma unroll
    for (int mi = 0; mi < 4; mi++) {
#pragma unroll
        for (int j = 0; j < 4; j++) {
            int r = wm * 64 + mi * 16 + fo * 4 + j;
            int grow = m0 + r;
            if (ROUTED && grow >= M) continue;
#pragma unroll
            for (int nj = 0; nj < 2; nj++) {
                int c = n0 + wn * 32 + nj * 16 + fr;
                float g = ag[mi][nj][j];
                float u = au[mi][nj][j];
                float h = (g / (1.f + __expf(-g))) * u;
                hout[(size_t)(obase + grow) * Ntot + c] = f2bf(h);
            }
        }
    }
}

// Down-projection GEMM. BM=128, BN=128, BK=64, 256 thr, 4 waves (64x64 each).
template <bool ROUTED>
__global__ __launch_bounds__(256) void k_down(
    const unsigned short* __restrict__ Ain,
    const float* __restrict__ Wdb,
    float* __restrict__ outp,
    const int* __restrict__ cnt, const int* __restrict__ offs,
    const int* __restrict__ etok, const float* __restrict__ ew) {
    constexpr int Kd = ROUTED ? INTER : SINTER;
    constexpr int KT = Kd / 64;
    const int e = ROUTED ? blockIdx.z : 0;
    const int n0 = blockIdx.x * 128;
    const int m0 = blockIdx.y * 128;
    int M, ibase;
    if (ROUTED) {
        M = cnt[e];
        if (m0 >= M) return;
        ibase = offs[e];
    } else { M = TTOK; ibase = 0; }

    const unsigned short* A = Ain + (size_t)ibase * Kd;
    const float* W = Wdb + (ROUTED ? (size_t)e * HID * INTER : (size_t)0) + (size_t)n0 * Kd;

    __shared__ alignas(16) unsigned short sA[128 * 64];
    __shared__ alignas(16) unsigned short sB[128 * 64];

    const int t = threadIdx.x;
    const unsigned short* srcA[4];
    unsigned wAo[4];
#pragma unroll
    for (int p = 0; p < 4; p++) {
        int r = p * 32 + (t >> 3);
        int row = m0 + r;
        if (ROUTED && row >= M) row = m0;
        srcA[p] = A + (size_t)row * Kd + (t & 7) * 8;
        wAo[p] = swz((unsigned)(r * 128 + (t & 7) * 16));
    }
    const float* srcB[8];
    unsigned wBo[8];
#pragma unroll
    for (int p = 0; p < 8; p++) {
        int r = p * 16 + (t >> 4);
        srcB[p] = W + (size_t)r * Kd + (t & 15) * 4;
        wBo[p] = swz((unsigned)(r * 128 + (t & 15) * 8));
    }

    uint4 ra[4]; float4 rb[8];
    auto load = [&](int k0) {
#pragma unroll
        for (int p = 0; p < 4; p++) ra[p] = *(const uint4*)(srcA[p] + k0);
#pragma unroll
        for (int p = 0; p < 8; p++) rb[p] = *(const float4*)(srcB[p] + k0);
    };
    auto store = [&]() {
#pragma unroll
        for (int p = 0; p < 4; p++) *(uint4*)((char*)sA + wAo[p]) = ra[p];
#pragma unroll
        for (int p = 0; p < 8; p++) {
            ushort4 v;
            v.x = f2bf(rb[p].x); v.y = f2bf(rb[p].y); v.z = f2bf(rb[p].z); v.w = f2bf(rb[p].w);
            *(ushort4*)((char*)sB + wBo[p]) = v;
        }
    };

    const int lane = t & 63;
    const int wid = t >> 6;
    const int wm = wid >> 1, wn = wid & 1;
    const int fr = lane & 15, fo = lane >> 4;

    unsigned aoff[4][2], boff[4][2];
#pragma unroll
    for (int mi = 0; mi < 4; mi++)
#pragma unroll
        for (int ks = 0; ks < 2; ks++)
            aoff[mi][ks] = swz((unsigned)((wm * 64 + mi * 16 + fr) * 128 + ks * 64 + fo * 16));
#pragma unroll
    for (int nj = 0; nj < 4; nj++)
#pragma unroll
        for (int ks = 0; ks < 2; ks++)
            boff[nj][ks] = swz((unsigned)((wn * 64 + nj * 16 + fr) * 128 + ks * 64 + fo * 16));

    f32x4 ac[4][4];
#pragma unroll
    for (int mi = 0; mi < 4; mi++)
#pragma unroll
        for (int nj = 0; nj < 4; nj++) ac[mi][nj] = {0.f, 0.f, 0.f, 0.f};

    load(0);
    store();
    __syncthreads();
    for (int kk = 0; kk < KT; ++kk) {
        if (kk + 1 < KT) load((kk + 1) * 64);
#pragma unroll
        for (int ks = 0; ks < 2; ++ks) {
            bf16x8 af[4], bf[4];
#pragma unroll
            for (int mi = 0; mi < 4; mi++)
                af[mi] = *(const bf16x8*)((const char*)sA + aoff[mi][ks]);
#pragma unroll
            for (int nj = 0; nj < 4; nj++)
                bf[nj] = *(const bf16x8*)((const char*)sB + boff[nj][ks]);
#pragma unroll
            for (int mi = 0; mi < 4; mi++)
#pragma unroll
                for (int nj = 0; nj < 4; nj++)
                    ac[mi][nj] = __builtin_amdgcn_mfma_f32_16x16x32_bf16(af[mi], bf[nj], ac[mi][nj], 0, 0, 0);
        }
        __syncthreads();
        if (kk + 1 < KT) store();
        __syncthreads();
    }

#pragma unroll
    for (int mi = 0; mi < 4; mi++) {
#pragma unroll
        for (int j = 0; j < 4; j++) {
            int r = wm * 64 + mi * 16 + fo * 4 + j;
            int grow = m0 + r;
            if (ROUTED) {
                if (grow >= M) continue;
                int entry = etok[e * TTOK + grow];
                float wt = ew[e * TTOK + grow];
                float* orow = outp + ((size_t)((entry & 1) * TTOK + (entry >> 1))) * HID;
#pragma unroll
                for (int nj = 0; nj < 4; nj++) {
                    int c = n0 + wn * 64 + nj * 16 + fr;
                    orow[c] = ac[mi][nj][j] * wt;
                }
            } else {
                float* orow = outp + (size_t)grow * HID;
#pragma unroll
                for (int nj = 0; nj < 4; nj++) {
                    int c = n0 + wn * 64 + nj * 16 + fr;
                    orow[c] = ac[mi][nj][j];
                }
            }
        }
    }
}

__global__ __launch_bounds__(256) void k_final(float* __restrict__ out,
                                               const float* __restrict__ slots) {
    size_t i = ((size_t)blockIdx.x * 256 + threadIdx.x) * 4;
    float4 o = *(float4*)(out + i);
    float4 s0 = *(const float4*)(slots + i);
    float4 s1 = *(const float4*)(slots + (size_t)TTOK * HID + i);
    o.x += s0.x + s1.x;
    o.y += s0.y + s1.y;
    o.z += s0.z + s1.z;
    o.w += s0.w + s1.w;
    *(float4*)(out + i) = o;
}

extern "C" void kernel_launch(void* const* d_in, const int* in_sizes, int n_in,
                              void* d_out, int out_size, void* d_ws, size_t ws_size,
                              hipStream_t stream) {
    const float* x = (const float*)d_in[0];
    const float* gate_w = (const float*)d_in[1];
    const float* cls_w = (const float*)d_in[2];
    const float* escale = (const float*)d_in[3];
    const float* ebias = (const float*)d_in[4];
    const float* wg = (const float*)d_in[5];
    const float* wu = (const float*)d_in[6];
    const float* wd = (const float*)d_in[7];
    const float* sg = (const float*)d_in[8];
    const float* su = (const float*)d_in[9];
    const float* sd = (const float*)d_in[10];
    float* out = (float*)d_out;

    char* ws = (char*)d_ws;
    size_t o = 0;
    auto alloc = [&](size_t bytes) {
        char* p = ws + o;
        o += (bytes + 255) & ~(size_t)255;
        return p;
    };
    unsigned short* xb   = (unsigned short*)alloc((size_t)TTOK * HID * 2);     // 8 MB
    unsigned short* hbuf = (unsigned short*)alloc((size_t)TTOK * SINTER * 2);  // 11.5 MB
    unsigned short* abuf = (unsigned short*)alloc((size_t)2 * TTOK * INTER * 2); // 11.5 MB
    float* slots         = (float*)alloc((size_t)2 * TTOK * HID * 4);          // 32 MB
    int* cnt             = (int*)alloc(256);
    int* offs            = (int*)alloc(256);
    int* etok            = (int*)alloc((size_t)NEXP * TTOK * 4);
    float* ew            = (float*)alloc((size_t)NEXP * TTOK * 4);

    k_zero<<<1, 64, 0, stream>>>(cnt);
    k_xcvt<<<2048, 256, 0, stream>>>(x, xb);
    k_router<<<512, 256, 0, stream>>>(x, gate_w, cls_w, escale, ebias, cnt, etok, ew);
    k_offsets<<<1, 64, 0, stream>>>(cnt, offs);
    // shared expert: gate+up then down (down writes z directly into d_out)
    k_glu<false><<<dim3(SINTER / 64, TTOK / 128, 1), 256, 0, stream>>>(
        xb, sg, su, hbuf, nullptr, nullptr, nullptr);
    // routed experts (grouped, worst-case grid with early exit)
    k_glu<true><<<dim3(INTER / 64, TTOK / 128, NEXP), 256, 0, stream>>>(
        xb, wg, wu, abuf, cnt, offs, etok);
    k_down<false><<<dim3(HID / 128, TTOK / 128, 1), 256, 0, stream>>>(
        hbuf, sd, out, nullptr, nullptr, nullptr, nullptr);
    k_down<true><<<dim3(HID / 128, TTOK / 128, NEXP), 256, 0, stream>>>(
        abuf, wd, slots, cnt, offs, etok, ew);
    k_final<<<4096, 256, 0, stream>>>(out, slots);
}